// Round 13
// baseline (131.038 us; speedup 1.0000x reference)
//
#include <hip/hip_runtime.h>

// Problem constants (from reference setup)
#define NB 128            // batches
#define NA 29             // atoms per batch
#define BN (NB*NA)        // 3712 nodes
#define FD 64             // feature dim
#define NBLK 464          // grid: 8 nodes per block (464*8 = 3712)

// ws layout (floats): x[BN*512] only (~7.6 MB). y lives in LDS.

// ---------------------------------------------------------------------------
// 20-path Clebsch-Gordan tensor product at one feature index.
// ---------------------------------------------------------------------------
__device__ __forceinline__ void tp20(const float* a, const float* bb,
                                     const float* w, float* o)
{
  #pragma unroll
  for (int p1 = 0; p1 < 2; ++p1) {
    #pragma unroll
    for (int p2 = 0; p2 < 2; ++p2) {
      const float* w5 = w + 5*(2*p1 + p2);
      const float s1 = a[p1*4+0], x1 = a[p1*4+1], y1 = a[p1*4+2], z1 = a[p1*4+3];
      const float s2 = bb[p2*4+0], x2 = bb[p2*4+1], y2 = bb[p2*4+2], z2 = bb[p2*4+3];
      const int so = (p1 == p2) ? 0 : 4;   // dest parity for T1..T4
      const int vo = 4 - so;               // dest parity for T5 (cross)
      o[so+0] += w5[0]*(s1*s2) + w5[3]*(x1*x2 + y1*y2 + z1*z2);
      o[so+1] += w5[1]*(s1*x2) + w5[2]*(x1*s2);
      o[so+2] += w5[1]*(s1*y2) + w5[2]*(y1*s2);
      o[so+3] += w5[1]*(s1*z2) + w5[2]*(z1*s2);
      o[vo+1] += w5[4]*(y1*z2 - z1*y2);
      o[vo+2] += w5[4]*(z1*x2 - x1*z2);
      o[vo+3] += w5[4]*(x1*y2 - y1*x2);
    }
  }
}

// ---------------------------------------------------------------------------
// Stage one parity's 2 weight matrices (8192 floats) into LDS. 256 thr x 8 f4.
// ---------------------------------------------------------------------------
__device__ __forceinline__ void stage2(float* __restrict__ wst,
                                       const float* __restrict__ src, int tid)
{
  const float4* s = (const float4*)src;
  float4* d = (float4*)wst;
  #pragma unroll
  for (int i = 0; i < 8; ++i) d[tid + i*256] = s[tid + i*256];
}

// ---------------------------------------------------------------------------
// One-parity dense for TWO nodes from LDS-staged weights (lane g reads
// wst[sel][f][g]: 2-way bank alias = free; rA/rB = wave-private LDS rows,
// broadcast float4 reads).
// ---------------------------------------------------------------------------
__device__ __forceinline__ void denseP2(const float* __restrict__ wst,
                                        const float* __restrict__ rA,
                                        const float* __restrict__ rB,
                                        float bs, int g,
                                        float oA[4], float oB[4])
{
  float a0A = bs, a0B = bs;
  #pragma unroll
  for (int f4 = 0; f4 < 16; ++f4) {
    const float w0 = wst[(f4*4+0)*64+g], w1 = wst[(f4*4+1)*64+g];
    const float w2 = wst[(f4*4+2)*64+g], w3 = wst[(f4*4+3)*64+g];
    const float4 xA = *(const float4*)&rA[f4*4];
    const float4 xB = *(const float4*)&rB[f4*4];
    a0A += w0*xA.x + w1*xA.y + w2*xA.z + w3*xA.w;
    a0B += w0*xB.x + w1*xB.y + w2*xB.z + w3*xB.w;
  }
  oA[0] = a0A; oB[0] = a0B;
  float a1A = 0, a2A = 0, a3A = 0, a1B = 0, a2B = 0, a3B = 0;
  #pragma unroll
  for (int f4 = 0; f4 < 16; ++f4) {
    const float w0 = wst[4096+(f4*4+0)*64+g], w1 = wst[4096+(f4*4+1)*64+g];
    const float w2 = wst[4096+(f4*4+2)*64+g], w3 = wst[4096+(f4*4+3)*64+g];
    const float4 aA = *(const float4*)&rA[ 64+f4*4];
    const float4 bA = *(const float4*)&rA[128+f4*4];
    const float4 cA = *(const float4*)&rA[192+f4*4];
    const float4 aB = *(const float4*)&rB[ 64+f4*4];
    const float4 bB = *(const float4*)&rB[128+f4*4];
    const float4 cB = *(const float4*)&rB[192+f4*4];
    a1A += w0*aA.x + w1*aA.y + w2*aA.z + w3*aA.w;
    a2A += w0*bA.x + w1*bA.y + w2*bA.z + w3*bA.w;
    a3A += w0*cA.x + w1*cA.y + w2*cA.z + w3*cA.w;
    a1B += w0*aB.x + w1*aB.y + w2*aB.z + w3*aB.w;
    a2B += w0*bB.x + w1*bB.y + w2*bB.z + w3*bB.w;
    a3B += w0*cB.x + w1*cB.y + w2*cB.z + w3*cB.w;
  }
  oA[1] = a1A; oA[2] = a2A; oA[3] = a3A;
  oB[1] = a1B; oB[2] = a2B; oB[3] = a3B;
}

// ---------------------------------------------------------------------------
// fmsg phase: 8 tasks (nodes j + 464*t). Per task: 28-edge radial basis +
// projection (rads in LDS, W column in regs — loaded ONCE per phase, 8x less
// L2 than R11's per-node-block load) fused with message accumulation;
// 4-wave reduce -> y_sh[t] (LDS-resident, consumed by node phase in-block).
// overlay ov: rads[1792] | emb[1856] | yred[1024] | elu/el1mu/efc[84] | us[84]
// ---------------------------------------------------------------------------
template<bool LAST>
__device__ __forceinline__ void fmsg_phase(
    float* __restrict__ ov, float (*y_sh)[4][FD],
    const int* __restrict__ Z, const float* __restrict__ pos,
    const float* __restrict__ src,      // !LAST: embed; LAST: x
    const float* __restrict__ wtp, const float* __restrict__ Wb,
    float logc, int j, int tid, int lane, int wv)
{
  float* rads  = ov;
  float* emb   = ov + 1792;
  float* yred  = ov + 3648;            // [4][4][64]
  float* elu   = ov + 4672;
  float* el1mu = ov + 4700;
  float* efc   = ov + 4728;
  float* us    = ov + 4756;            // [28][3]
  const float kk = (float)lane;

  float wb[64];                        // W column for lane g, whole phase
  #pragma unroll
  for (int k = 0; k < 64; ++k) wb[k] = Wb[k*FD + lane];
  const float wm0 = wtp[0*FD + lane];
  const float wm1 = LAST ? 0.0f : wtp[1*FD + lane];
  const float wm3 = LAST ? wtp[3*FD + lane]  : 0.0f;
  const float wm5 = LAST ? wtp[10*FD + lane] : 0.0f;
  const float wm8 = LAST ? wtp[13*FD + lane] : 0.0f;

  for (int t = 0; t < 8; ++t) {
    const int bn = j + NBLK*t;
    const int b = bn / NA, n = bn - b*NA;
    __syncthreads();                   // prev task consumed / prologue done
    if (tid < 28) {
      const int jr = tid, jj = jr + (jr >= n ? 1 : 0);
      const float dx = pos[(b*NA+jj)*3+0] - pos[(b*NA+n)*3+0];
      const float dy = pos[(b*NA+jj)*3+1] - pos[(b*NA+n)*3+1];
      const float dz = pos[(b*NA+jj)*3+2] - pos[(b*NA+n)*3+2];
      const float r  = sqrtf(dx*dx + dy*dy + dz*dz + 1e-12f);
      const float ri = 1.0f / r;
      us[jr*3+0] = dx*ri; us[jr*3+1] = dy*ri; us[jr*3+2] = dz*ri;
      const float u = 1.0f/(1.0f + r);
      elu[jr]   = logf(u);
      el1mu[jr] = logf(fmaxf(1.0f - u, 1e-12f));
      const float x2 = (r*0.2f)*(r*0.2f);
      efc[jr] = (x2 < 1.0f) ? expf(1.0f - 1.0f/fmaxf(1.0f - x2, 1e-12f)) : 0.0f;
    }
    if constexpr (!LAST) {
      for (int idx = tid; idx < NA*FD; idx += 256)
        emb[idx] = src[Z[b*NA + (idx>>6)]*FD + (idx&63)];
    }
    __syncthreads();

    #pragma unroll
    for (int i = 0; i < 7; ++i) {      // wave-private rads rows
      const int e = wv*7 + i;
      rads[e*64 + lane] = expf(logc + kk*elu[e] + (63.0f - kk)*el1mu[e]) * efc[e];
    }
    float y0 = 0.0f, y1 = 0.0f, y2 = 0.0f, y3 = 0.0f, y4 = 0.0f;
    #pragma unroll
    for (int i = 0; i < 7; ++i) {
      const int jr = wv*7 + i;
      float a0 = 0.0f;                 // rp = radial . W[:,g] (same-wave RAW)
      #pragma unroll
      for (int k4 = 0; k4 < 16; ++k4) {
        const float4 rv = *(const float4*)&rads[jr*64 + k4*4];
        a0 += wb[k4*4+0]*rv.x + wb[k4*4+1]*rv.y + wb[k4*4+2]*rv.z + wb[k4*4+3]*rv.w;
      }
      const int jj = jr + (jr >= n ? 1 : 0);
      const float ux = us[jr*3+0], uy = us[jr*3+1], uz = us[jr*3+2];
      if constexpr (!LAST) {
        const float t0 = a0 * emb[jj*64 + lane];
        y0 += wm0*t0;
        const float t1 = wm1*t0;
        y1 += t1*ux; y2 += t1*uy; y3 += t1*uz;
      } else {
        const float* xj = src + (size_t)(b*NA + jj)*512 + lane;
        const float s1   = xj[0];
        const float dot1 = xj[64]*ux + xj[128]*uy + xj[192]*uz;
        const float s1p  = xj[256];
        const float dotp = xj[320]*ux + xj[384]*uy + xj[448]*uz;
        y0 += a0*(wm0*s1  + wm3*dot1);
        y4 += a0*(wm5*s1p + wm8*dotp);
      }
    }
    if constexpr (!LAST) {
      yred[(wv*4+0)*64+lane] = y0; yred[(wv*4+1)*64+lane] = y1;
      yred[(wv*4+2)*64+lane] = y2; yred[(wv*4+3)*64+lane] = y3;
    } else {
      yred[(wv*4+0)*64+lane] = y0; yred[(wv*4+1)*64+lane] = y4;
    }
    __syncthreads();
    if (wv == 0) {
      const int nch = LAST ? 2 : 4;
      for (int c = 0; c < nch; ++c) {
        y_sh[t][c][lane] = yred[(0*4+c)*64+lane] + yred[(1*4+c)*64+lane]
                         + yred[(2*4+c)*64+lane] + yred[(3*4+c)*64+lane];
      }
    }
  }
  __syncthreads();                     // y_sh complete for all 8 tasks
}

// ---------------------------------------------------------------------------
// node phase: 8 nodes per block, wave r owns nodes j+464*(2r), j+464*(2r+1).
// Weights staged in LDS 2-mat chunks; y from LDS (y_sh). iter0 parity-1
// dense pipeline = precomputed c4 constant (x0/y pseudo channels exactly 0).
// overlay ov: wst[8192] | rows[4096]
// ---------------------------------------------------------------------------
template<bool LAST>
__device__ __forceinline__ void node_phase(
    float* __restrict__ ov, float (*y_sh)[4][FD],
    const float* __restrict__ c4_sh,
    const int* __restrict__ Z, const float* __restrict__ embed,
    const float* __restrict__ Ef,
    const float* __restrict__ d1w, const float* __restrict__ d1b,
    const float* __restrict__ d2w, const float* __restrict__ d2b,
    const float* __restrict__ tens_w, const float* __restrict__ tdw,
    const float* __restrict__ td_tp_w, const float* __restrict__ out_w,
    const float* __restrict__ ebias,
    float* __restrict__ xg, float* __restrict__ out, int j, int tid)
{
  float* wst  = ov;
  float* rows = ov + 8192;
  const int r = tid >> 6, g = tid & 63;
  const int iA = 2*r, iB = iA + 1;
  const int ndA = j + NBLK*iA, ndB = j + NBLK*iB;
  float* rowA = rows + iA*512;
  float* rowB = rows + iB*512;

  // ---- x1 = x + y (y from LDS; rows are wave-private)
  float yA[4], yB[4];
  float y0A = 0, y4A = 0, y0B = 0, y4B = 0;
  if constexpr (!LAST) {
    #pragma unroll
    for (int c = 0; c < 4; ++c) { yA[c] = y_sh[iA][c][g]; yB[c] = y_sh[iB][c][g]; }
    rowA[g] = embed[Z[ndA]*FD + g] + yA[0];
    rowB[g] = embed[Z[ndB]*FD + g] + yB[0];
    #pragma unroll
    for (int c = 1; c < 4; ++c) { rowA[c*64+g] = yA[c]; rowB[c*64+g] = yB[c]; }
  } else {
    y0A = y_sh[iA][0][g]; y4A = y_sh[iA][1][g];
    y0B = y_sh[iB][0][g]; y4B = y_sh[iB][1][g];
    #pragma unroll
    for (int pc = 0; pc < 8; ++pc) {
      float vA = xg[(size_t)ndA*512 + pc*64 + g];
      float vB = xg[(size_t)ndB*512 + pc*64 + g];
      if (pc == 0) { vA += y0A; vB += y0B; }
      if (pc == 4) { vA += y4A; vB += y4B; }
      rowA[pc*64+g] = vA; rowB[pc*64+g] = vB;
    }
  }
  stage2(wst, d1w, tid);                // d1 parity-0
  __syncthreads();

  // ---- h = silu(d1(x1)), parity 0
  {
    float hA[4], hB[4];
    denseP2(wst, rowA, rowB, d1b[g], g, hA, hB);
    const float sA = 1.0f/(1.0f + expf(-hA[0]));
    const float sB = 1.0f/(1.0f + expf(-hB[0]));
    rowA[g] = hA[0]*sA; rowB[g] = hB[0]*sB;
    #pragma unroll
    for (int c = 1; c < 4; ++c) { rowA[c*64+g] = hA[c]*sA; rowB[c*64+g] = hB[c]*sB; }
  }
  __syncthreads();
  if constexpr (LAST) {                 // parity 1 of d1 (iter0 skips: input 0)
    stage2(wst, d1w + 8192, tid);
    __syncthreads();
    float hA[4], hB[4];
    denseP2(wst, rowA + 256, rowB + 256, d1b[64+g], g, hA, hB);
    const float sA = 1.0f/(1.0f + expf(-hA[0]));
    const float sB = 1.0f/(1.0f + expf(-hB[0]));
    rowA[256+g] = hA[0]*sA; rowB[256+g] = hB[0]*sB;
    #pragma unroll
    for (int c = 1; c < 4; ++c) { rowA[256+c*64+g] = hA[c]*sA; rowB[256+c*64+g] = hB[c]*sB; }
    __syncthreads();
  }
  stage2(wst, d2w, tid);                // d2 parity-0
  __syncthreads();

  // ---- x2 = d2(h) + y
  float x2A[8], x2B[8];
  {
    float oA[4], oB[4];
    denseP2(wst, rowA, rowB, d2b[g], g, oA, oB);
    #pragma unroll
    for (int c = 0; c < 4; ++c) { x2A[c] = oA[c]; x2B[c] = oB[c]; }
  }
  if constexpr (!LAST) {
    #pragma unroll
    for (int c = 0; c < 4; ++c) { x2A[c] += yA[c]; x2B[c] += yB[c]; }
    const float c4v = c4_sh[g];
    x2A[4] = c4v; x2B[4] = c4v;
    x2A[5] = x2A[6] = x2A[7] = 0.0f;
    x2B[5] = x2B[6] = x2B[7] = 0.0f;
  } else {
    x2A[0] += y0A; x2B[0] += y0B;
    __syncthreads();
    stage2(wst, d2w + 8192, tid);       // d2 parity-1
    __syncthreads();
    float oA[4], oB[4];
    denseP2(wst, rowA + 256, rowB + 256, d2b[64+g], g, oA, oB);
    x2A[4] = oA[0] + y4A; x2A[5] = oA[1]; x2A[6] = oA[2]; x2A[7] = oA[3];
    x2B[4] = oB[0] + y4B; x2B[5] = oB[1]; x2B[6] = oB[2]; x2B[7] = oB[3];
  }

  // ---- x3 = x2 + tp(x2, xEF, tens_w) -> rows (full 8 channels)
  float x3A[8], x3B[8];
  {
    float w20[20];
    #pragma unroll
    for (int q = 0; q < 20; ++q) w20[q] = tens_w[q*FD + g];
    const int bA = ndA / NA, bB = ndB / NA;
    {
      const float bbv[8] = {1.0f, Ef[bA*3+0], Ef[bA*3+1], Ef[bA*3+2],
                            1.0f, Ef[bA*3+0], Ef[bA*3+1], Ef[bA*3+2]};
      float o[8] = {0,0,0,0,0,0,0,0};
      tp20(x2A, bbv, w20, o);
      #pragma unroll
      for (int pc = 0; pc < 8; ++pc) { x3A[pc] = x2A[pc] + o[pc]; rowA[pc*64+g] = x3A[pc]; }
    }
    {
      const float bbv[8] = {1.0f, Ef[bB*3+0], Ef[bB*3+1], Ef[bB*3+2],
                            1.0f, Ef[bB*3+0], Ef[bB*3+1], Ef[bB*3+2]};
      float o[8] = {0,0,0,0,0,0,0,0};
      tp20(x2B, bbv, w20, o);
      #pragma unroll
      for (int pc = 0; pc < 8; ++pc) { x3B[pc] = x2B[pc] + o[pc]; rowB[pc*64+g] = x3B[pc]; }
    }
  }
  __syncthreads();
  stage2(wst, tdw, tid);                // td parity-0
  __syncthreads();

  // ---- td = dense(x3, tdw)
  float tdA[8], tdB[8];
  {
    float oA[4], oB[4];
    denseP2(wst, rowA, rowB, 0.0f, g, oA, oB);
    #pragma unroll
    for (int c = 0; c < 4; ++c) { tdA[c] = oA[c]; tdB[c] = oB[c]; }
  }
  __syncthreads();
  stage2(wst, tdw + 8192, tid);         // td parity-1
  __syncthreads();
  {
    float oA[4], oB[4];
    denseP2(wst, rowA + 256, rowB + 256, 0.0f, g, oA, oB);
    #pragma unroll
    for (int c = 0; c < 4; ++c) { tdA[4+c] = oA[c]; tdB[4+c] = oB[c]; }
  }

  // ---- x4 = tp(x3, td, td_tp_w) ; LAST: only scalar-regular -> energy
  if constexpr (LAST) {
    const float wa = td_tp_w[0*FD+g],  wb = td_tp_w[3*FD+g];
    const float wc = td_tp_w[15*FD+g], wd = td_tp_w[18*FD+g];
    const float ow = out_w[g];
    float pA = ow * (wa*(x3A[0]*tdA[0])
                   + wb*(x3A[1]*tdA[1] + x3A[2]*tdA[2] + x3A[3]*tdA[3])
                   + wc*(x3A[4]*tdA[4])
                   + wd*(x3A[5]*tdA[5] + x3A[6]*tdA[6] + x3A[7]*tdA[7]));
    float pB = ow * (wa*(x3B[0]*tdB[0])
                   + wb*(x3B[1]*tdB[1] + x3B[2]*tdB[2] + x3B[3]*tdB[3])
                   + wc*(x3B[4]*tdB[4])
                   + wd*(x3B[5]*tdB[5] + x3B[6]*tdB[6] + x3B[7]*tdB[7]));
    #pragma unroll
    for (int off = 32; off > 0; off >>= 1) {
      pA += __shfl_xor(pA, off, 64);
      pB += __shfl_xor(pB, off, 64);
    }
    if (g == 0) {
      atomicAdd(&out[ndA/NA], pA + ebias[Z[ndA]]);
      atomicAdd(&out[ndB/NA], pB + ebias[Z[ndB]]);
    }
  } else {
    float w20[20];
    #pragma unroll
    for (int q = 0; q < 20; ++q) w20[q] = td_tp_w[q*FD + g];
    {
      float o[8] = {0,0,0,0,0,0,0,0};
      tp20(x3A, tdA, w20, o);
      #pragma unroll
      for (int pc = 0; pc < 8; ++pc) xg[(size_t)ndA*512 + pc*64 + g] = o[pc];
    }
    {
      float o[8] = {0,0,0,0,0,0,0,0};
      tp20(x3B, tdB, w20, o);
      #pragma unroll
      for (int pc = 0; pc < 8; ++pc) xg[(size_t)ndB*512 + pc*64 + g] = o[pc];
    }
  }
}

// ---------------------------------------------------------------------------
// One iteration per launch: fmsg + node fused (y stays in LDS; block j owns
// nodes {j+464t} in both phases). The cross-block dependency (node0's x ->
// fmsg1) is handled by the kernel boundary — ordinary launches, no
// cooperative kernel (R12: hipLaunchCooperativeKernel silently never ran
// under graph capture; failure signature identical to the round-0 stub).
// iter0 prologue: zero out (iter1's atomics accumulate; harness doesn't
// re-zero between replays) + c4 constant.
// ---------------------------------------------------------------------------
template<bool LAST>
__global__ __launch_bounds__(256) void iter_kernel(
    const int*   __restrict__ Z,
    const float* __restrict__ pos,
    const float* __restrict__ Ef,
    const float* __restrict__ embed,
    const float* __restrict__ mpbw,   // iteration slice [64][64]
    const float* __restrict__ mptpw,  // iteration slice [20][64]
    const float* __restrict__ d1w, const float* __restrict__ d1b,
    const float* __restrict__ d2w, const float* __restrict__ d2b,
    const float* __restrict__ tensw,
    const float* __restrict__ tdw,
    const float* __restrict__ tdtpw,
    const float* __restrict__ outw,
    const float* __restrict__ ebias,
    float* __restrict__ xg,
    float* __restrict__ out)
{
  __shared__ float4 ovb[3072];          // 48 KB phase overlay
  __shared__ float y_sh[8][4][FD];      // 8 KB, persists fmsg->node
  __shared__ float c4_sh[FD];
  float* ov = (float*)ovb;

  const int j = blockIdx.x, tid = threadIdx.x, lane = tid & 63, wv = tid >> 6;
  const float kk = (float)lane;
  const float logc = lgammaf(64.0f) - lgammaf(kk + 1.0f) - lgammaf(64.0f - kk);

  if constexpr (!LAST) {
    // zero energy output (consumed by iter1's atomics, stream-ordered)
    if (j < NB && tid == 0) out[j] = 0.0f;
    // c4[g] = d2b[p1][g] + sum_f d2w[p1][sel0][f][g] * silu(d1b[p1][f]):
    // the whole iter-0 parity-1 dense pipeline (pseudo inputs exactly 0)
    float* sil = ov;                    // prologue-only scratch
    if (tid < 64) { const float v = d1b[64+tid]; sil[tid] = v/(1.0f + expf(-v)); }
    __syncthreads();
    if (tid < 64) {
      float acc = d2b[64 + tid];
      for (int f = 0; f < 64; ++f) acc += d2w[8192 + f*64 + tid] * sil[f];
      c4_sh[tid] = acc;
    }
  }                                     // fmsg task-entry barrier orders overwrite

  const float* src = LAST ? xg : embed;
  fmsg_phase<LAST>(ov, y_sh, Z, pos, src, mptpw, mpbw, logc, j, tid, lane, wv);
  node_phase<LAST>(ov, y_sh, c4_sh, Z, embed, Ef, d1w, d1b, d2w, d2b,
                   tensw, tdw, tdtpw, outw, ebias, xg, out, j, tid);
}

// ---------------------------------------------------------------------------
extern "C" void kernel_launch(void* const* d_in, const int* in_sizes, int n_in,
                              void* d_out, int out_size, void* d_ws, size_t ws_size,
                              hipStream_t stream)
{
  (void)in_sizes; (void)n_in; (void)out_size; (void)ws_size;
  const int*   Z     = (const int*)  d_in[0];
  const float* pos   = (const float*)d_in[1];
  const float* Ef    = (const float*)d_in[2];
  // d_in[3]/d_in[4] (dst_idx/src_idx): full i!=j meshgrid, reproduced analytically.
  const float* embed = (const float*)d_in[5];
  const float* mpbw  = (const float*)d_in[6];
  const float* mptpw = (const float*)d_in[7];
  const float* d1w   = (const float*)d_in[8];
  const float* d1b   = (const float*)d_in[9];
  const float* d2w   = (const float*)d_in[10];
  const float* d2b   = (const float*)d_in[11];
  const float* tensw = (const float*)d_in[12];
  const float* tdw   = (const float*)d_in[13];
  const float* tdtpw = (const float*)d_in[14];
  const float* outw  = (const float*)d_in[15];
  const float* ebias = (const float*)d_in[16];
  float* out = (float*)d_out;
  float* xg  = (float*)d_ws;            // BN*512 floats (~7.6 MB)

  iter_kernel<false><<<NBLK, 256, 0, stream>>>(Z, pos, Ef, embed,
      mpbw, mptpw, d1w, d1b, d2w, d2b, tensw, tdw, tdtpw, outw, ebias,
      xg, out);
  iter_kernel<true><<<NBLK, 256, 0, stream>>>(Z, pos, Ef, embed,
      mpbw + 4096, mptpw + 1280, d1w + 16384, d1b + 128, d2w + 16384,
      d2b + 128, tensw + 1280, tdw + 16384, tdtpw + 1280, outw, ebias,
      xg, out);
}